// Round 18
// baseline (105.241 us; speedup 1.0000x reference)
//
#include <hip/hip_runtime.h>
#include <hip/hip_bf16.h>
#include <stdint.h>

typedef unsigned short u16;
typedef unsigned int u32;
typedef unsigned long long u64;
typedef float f32x4 __attribute__((ext_vector_type(4)));
typedef float f32x16 __attribute__((ext_vector_type(16)));
typedef short bf16x8 __attribute__((ext_vector_type(8)));
typedef u32 u32x4 __attribute__((ext_vector_type(4)));

#define MFMA(a, b, c) __builtin_amdgcn_mfma_f32_16x16x32_bf16((a), (b), (c), 0, 0, 0)
#define MFMA32(a, b, c) __builtin_amdgcn_mfma_f32_32x32x16_bf16((a), (b), (c), 0, 0, 0)

__device__ __forceinline__ void gll16(const void* g, void* lds) {
  __builtin_amdgcn_global_load_lds(
      (const __attribute__((address_space(1))) u32*)(uintptr_t)g,
      (__attribute__((address_space(3))) u32*)(uintptr_t)lds, 16, 0, 0);
}

__device__ __forceinline__ u16 f2b(float f) {
  union { __hip_bfloat16 h; u16 u; } cv;
  cv.h = __float2bfloat16(f);
  return cv.u;
}
__device__ __forceinline__ float b2f(u16 b) {
  union { u32 u; float f; } cv;
  cv.u = (u32)b << 16;
  return cv.f;
}
__device__ __forceinline__ u32 cvtpk(float lo, float hi) {
  u32 r;
  asm("v_cvt_pk_bf16_f32 %0, %1, %2" : "=v"(r) : "v"(lo), "v"(hi));
  return r;
}

// swizzle: conflict-free for both transpose-writes and column-slice reads
__device__ __forceinline__ int sw(int r) { return ((r ^ (r >> 3)) & 7) << 4; }

// ---------------- fused prep: cvt(x) + trcvt(wa) + trcvt(wp) -------------
// blocks [0,4096): x fp32 -> bf16 elementwise.
// blocks [4096,4864): wa [1024][3072] -> wat [3072][1024] bf16.
// blocks [4864,5120): wp [1024][1024] -> wpt [1024][1024] bf16.
__global__ __launch_bounds__(256) void k_prep(const float* __restrict__ x,
                                              u16* __restrict__ xb,
                                              const float* __restrict__ wa,
                                              u16* __restrict__ wat,
                                              const float* __restrict__ wp,
                                              u16* __restrict__ wpt) {
  const int bid = blockIdx.x;
  const int tid = threadIdx.x;
  if (bid < 4096) {
    const int i = bid * 256 + tid;
    const float4 v = reinterpret_cast<const float4*>(x)[i];
    u32 lo = (u32)f2b(v.x) | ((u32)f2b(v.y) << 16);
    u32 hi = (u32)f2b(v.z) | ((u32)f2b(v.w) << 16);
    reinterpret_cast<uint2*>(xb)[i] = make_uint2(lo, hi);
    return;
  }
  // tiled transpose sections
  const float* in;
  u16* out;
  int R, C, bx, by;
  if (bid < 4864) {
    const int idx = bid - 4096;
    in = wa; out = wat; R = 1024; C = 3072;
    bx = idx % 48; by = idx / 48;
  } else {
    const int idx = bid - 4864;
    in = wp; out = wpt; R = 1024; C = 1024;
    bx = idx & 15; by = idx >> 4;
  }
  __shared__ float tile[64][65];
  const int r0 = by * 64, c0 = bx * 64;
  const int tr = tid >> 4;
  const int tc4 = (tid & 15) * 4;
#pragma unroll
  for (int i = 0; i < 4; ++i) {
    const float4 v = *reinterpret_cast<const float4*>(
        &in[(size_t)(r0 + i * 16 + tr) * C + c0 + tc4]);
    tile[i * 16 + tr][tc4 + 0] = v.x;
    tile[i * 16 + tr][tc4 + 1] = v.y;
    tile[i * 16 + tr][tc4 + 2] = v.z;
    tile[i * 16 + tr][tc4 + 3] = v.w;
  }
  __syncthreads();
#pragma unroll
  for (int i = 0; i < 4; ++i) {
    const int c = i * 16 + tr;
    const int r4 = tc4;
    u32 lo = (u32)f2b(tile[r4 + 0][c]) | ((u32)f2b(tile[r4 + 1][c]) << 16);
    u32 hi = (u32)f2b(tile[r4 + 2][c]) | ((u32)f2b(tile[r4 + 3][c]) << 16);
    *reinterpret_cast<uint2*>(&out[(size_t)(c0 + c) * R + r0 + r4]) =
        make_uint2(lo, hi);
  }
}

// ---------------- GEMM1: qkv = x @ w_attn, 4096x3072x1024 ----------------
// 256x192 tile, 512 thr / 8 waves, BK=64, dbuf LDS, 4-phase interleave.
__global__ __launch_bounds__(512, 1) void k_gemm1(const u16* __restrict__ A,
                                                  const u16* __restrict__ Bt,
                                                  u16* __restrict__ C) {
  __shared__ u16 As[2][256 * 64];  // 32KB each, rows 128B, sw-swizzled
  __shared__ u16 Bs[2][192 * 64];  // 24KB each
  const int tid = threadIdx.x;
  const int lane = tid & 63;
  const int w = tid >> 6;
  const int wm = w >> 2, wn = w & 3;
  const int l15 = lane & 15, lg = lane >> 4;

  const int bid = blockIdx.x;                 // 0..255
  const int lin = (bid & 7) * 32 + (bid >> 3);  // XCD-chunked
  const int bm = lin >> 4, bn = lin & 15;
  const size_t brow = (size_t)bm * 256, bcol = (size_t)bn * 192;

  const int sr = tid >> 3;                  // 0..63
  const int scb = (tid & 7) * 16;           // bytes
  const int gcol = (scb ^ sw(sr)) >> 1;     // u16 units
  const u16* Ag[4];
#pragma unroll
  for (int i = 0; i < 4; ++i) Ag[i] = A + (brow + i * 64 + sr) * 1024 + gcol;
  const u16* Bg[3];
#pragma unroll
  for (int i = 0; i < 3; ++i) Bg[i] = Bt + (bcol + i * 64 + sr) * 1024 + gcol;

  f32x4 acc[8][3] = {};

#pragma unroll
  for (int i = 0; i < 4; ++i) gll16(Ag[i], (char*)As[0] + i * 8192 + tid * 16);
#pragma unroll
  for (int i = 0; i < 3; ++i) gll16(Bg[i], (char*)Bs[0] + i * 8192 + tid * 16);
  asm volatile("s_waitcnt vmcnt(0) lgkmcnt(0)" ::: "memory");
  __builtin_amdgcn_s_barrier();
  __builtin_amdgcn_sched_barrier(0);

  for (int kt = 0; kt < 16; ++kt) {
    const int cur = kt & 1;
    const char* as = (const char*)As[cur];
    const char* bs = (const char*)Bs[cur];
    char* asn = (char*)As[cur ^ 1];
    char* bsn = (char*)Bs[cur ^ 1];
    const bool more = (kt + 1 < 16);
    const int ko = (kt + 1) * 64;

    bf16x8 bfr[3][2];
#pragma unroll
    for (int n = 0; n < 3; ++n) {
      const int row = wn * 48 + n * 16 + l15;
#pragma unroll
      for (int kh = 0; kh < 2; ++kh)
        bfr[n][kh] = *(const bf16x8*)(bs + row * 128 +
                                      ((kh * 64 + lg * 16) ^ sw(row)));
    }
#define GPHASE(MB, STAGE_A, STAGE_B, LAST)                                    \
    {                                                                         \
      bf16x8 af[2][2];                                                        \
      _Pragma("unroll")                                                       \
      for (int mm = 0; mm < 2; ++mm) {                                        \
        const int row = wm * 128 + (MB + mm) * 16 + l15;                      \
        _Pragma("unroll")                                                     \
        for (int kh = 0; kh < 2; ++kh)                                        \
          af[mm][kh] = *(const bf16x8*)(as + row * 128 +                      \
                                        ((kh * 64 + lg * 16) ^ sw(row)));     \
      }                                                                       \
      if (STAGE_A && more) {                                                  \
        _Pragma("unroll")                                                     \
        for (int i = 0; i < 4; ++i)                                           \
          gll16(Ag[i] + ko, asn + i * 8192 + tid * 16);                       \
      }                                                                       \
      if (STAGE_B && more) {                                                  \
        _Pragma("unroll")                                                     \
        for (int i = 0; i < 3; ++i)                                           \
          gll16(Bg[i] + ko, bsn + i * 8192 + tid * 16);                       \
      }                                                                       \
      __builtin_amdgcn_s_setprio(1);                                          \
      _Pragma("unroll")                                                       \
      for (int mm = 0; mm < 2; ++mm)                                          \
        _Pragma("unroll")                                                     \
        for (int n = 0; n < 3; ++n) {                                         \
          acc[MB + mm][n] = MFMA(af[mm][0], bfr[n][0], acc[MB + mm][n]);      \
          acc[MB + mm][n] = MFMA(af[mm][1], bfr[n][1], acc[MB + mm][n]);      \
        }                                                                     \
      __builtin_amdgcn_s_setprio(0);                                          \
      if (LAST) {                                                             \
        asm volatile("s_waitcnt vmcnt(0) lgkmcnt(0)" ::: "memory");           \
      }                                                                       \
      __builtin_amdgcn_s_barrier();                                           \
    }
    GPHASE(0, 1, 0, 0)
    GPHASE(2, 0, 1, 0)
    GPHASE(4, 0, 0, 0)
    GPHASE(6, 0, 0, 1)
#undef GPHASE
    __builtin_amdgcn_sched_barrier(0);
  }

#pragma unroll
  for (int m = 0; m < 8; ++m) {
    const size_t row = brow + wm * 128 + m * 16 + lg * 4;
#pragma unroll
    for (int n = 0; n < 3; ++n) {
      const size_t col = bcol + wn * 48 + n * 16 + l15;
#pragma unroll
      for (int r = 0; r < 4; ++r)
        C[(row + r) * 3072 + col] = f2b(acc[m][n][r]);
    }
  }
}

// ---------------- GEMM2: out = y @ w_proj, 4096x1024x1024, fp32 out ------
__global__ __launch_bounds__(256) void k_gemm2(const u16* __restrict__ A,
                                               const u16* __restrict__ Bt,
                                               float* __restrict__ C) {
  __shared__ u16 As[2][128 * 64];
  __shared__ u16 Bs[2][128 * 64];
  const int tid = threadIdx.x;
  const int lane = tid & 63;
  const int w = tid >> 6;
  const int wm = w >> 1, wn = w & 1;
  const int l15 = lane & 15, lg = lane >> 4;

  const int bid = blockIdx.x;
  const int lin = (bid & 7) * 32 + (bid >> 3);
  const int bm = lin >> 3, bn = lin & 7;
  const size_t brow = (size_t)bm * 128, bcol = (size_t)bn * 128;

  const int sr = tid >> 3;
  const int scb = (tid & 7) * 16;
  const u16* Ag[4];
  const u16* Bg[4];
#pragma unroll
  for (int i = 0; i < 4; ++i) {
    const int row = i * 32 + sr;
    const int gcol = (scb ^ sw(row)) >> 1;
    Ag[i] = A + (brow + row) * 1024 + gcol;
    Bg[i] = Bt + (bcol + row) * 1024 + gcol;
  }

  f32x4 acc[4][4] = {};

#pragma unroll
  for (int i = 0; i < 4; ++i) gll16(Ag[i], (char*)As[0] + i * 4096 + tid * 16);
#pragma unroll
  for (int i = 0; i < 4; ++i) gll16(Bg[i], (char*)Bs[0] + i * 4096 + tid * 16);
  asm volatile("s_waitcnt vmcnt(0) lgkmcnt(0)" ::: "memory");
  __builtin_amdgcn_s_barrier();
  __builtin_amdgcn_sched_barrier(0);

  for (int kt = 0; kt < 16; ++kt) {
    const int cur = kt & 1;
    const char* as = (const char*)As[cur];
    const char* bs = (const char*)Bs[cur];
    char* asn = (char*)As[cur ^ 1];
    char* bsn = (char*)Bs[cur ^ 1];
    const bool more = (kt + 1 < 16);
    const int ko = (kt + 1) * 64;

    bf16x8 bfr[4][2];
#pragma unroll
    for (int n = 0; n < 4; ++n) {
      const int row = wn * 64 + n * 16 + l15;
#pragma unroll
      for (int kh = 0; kh < 2; ++kh)
        bfr[n][kh] = *(const bf16x8*)(bs + row * 128 +
                                      ((kh * 64 + lg * 16) ^ sw(row)));
    }
#define G2PHASE(MB, STAGE_A, STAGE_B, LAST)                                   \
    {                                                                         \
      bf16x8 af[2];                                                           \
      {                                                                       \
        const int row = wm * 64 + (MB) * 16 + l15;                            \
        _Pragma("unroll")                                                     \
        for (int kh = 0; kh < 2; ++kh)                                        \
          af[kh] = *(const bf16x8*)(as + row * 128 +                          \
                                    ((kh * 64 + lg * 16) ^ sw(row)));         \
      }                                                                       \
      if (STAGE_A && more) {                                                  \
        _Pragma("unroll")                                                     \
        for (int i = 0; i < 4; ++i)                                           \
          gll16(Ag[i] + ko, asn + i * 4096 + tid * 16);                       \
      }                                                                       \
      if (STAGE_B && more) {                                                  \
        _Pragma("unroll")                                                     \
        for (int i = 0; i < 4; ++i)                                           \
          gll16(Bg[i] + ko, bsn + i * 4096 + tid * 16);                       \
      }                                                                       \
      __builtin_amdgcn_s_setprio(1);                                          \
      _Pragma("unroll")                                                       \
      for (int n = 0; n < 4; ++n) {                                           \
        acc[MB][n] = MFMA(af[0], bfr[n][0], acc[MB][n]);                      \
        acc[MB][n] = MFMA(af[1], bfr[n][1], acc[MB][n]);                      \
      }                                                                       \
      __builtin_amdgcn_s_setprio(0);                                          \
      if (LAST) {                                                             \
        asm volatile("s_waitcnt vmcnt(0) lgkmcnt(0)" ::: "memory");           \
      }                                                                       \
      __builtin_amdgcn_s_barrier();                                           \
    }
    G2PHASE(0, 1, 0, 0)
    G2PHASE(1, 0, 1, 0)
    G2PHASE(2, 0, 0, 0)
    G2PHASE(3, 0, 0, 1)
#undef G2PHASE
    __builtin_amdgcn_sched_barrier(0);
  }

#pragma unroll
  for (int m = 0; m < 4; ++m) {
    const size_t row = brow + wm * 64 + m * 16 + lg * 4;
#pragma unroll
    for (int n = 0; n < 4; ++n) {
      const size_t col = bcol + wn * 64 + n * 16 + l15;
#pragma unroll
      for (int r = 0; r < 4; ++r)
        C[(row + r) * 1024 + col] = acc[m][n][r];
    }
  }
}

// ---------------- fused causal flash attention (v13 = v12 + T5) ----------
// 512 blocks x 256 thr (4 waves), 64-row q-tiles paired (k,31-k) -> 33
// uniform steps, 2 desynced blocks/CU (40KB LDS, O-merge aliased).
// s_setprio(1) around the per-step MFMA cluster (T5).
__global__ __launch_bounds__(256, 2) void k_attn(const u16* __restrict__ qkv,
                                                 u16* __restrict__ y) {
  __shared__ char smem[40960];
  char* KlB = smem;                 // 3 x 8192  [t][d] sw(t)
  char* VtB = smem + 24576;         // 2 x 8192  [d][t] sw(d)
  float (*Om)[64][33] = (float (*)[64][33])smem;         // epilogue alias
  float (*Lm)[2][32] = (float (*)[2][32])(smem + 16896); // 512B

  const int tid = threadIdx.x;
  const int lane = tid & 63;
  const int w = tid >> 6;            // 0..3
  const int qsub = w & 1, tsub = w >> 1;
  const int l31 = lane & 31, hi = lane >> 5;

  const int bid = blockIdx.x;          // 0..511
  const int xcd = bid & 7;
  const int idx = bid >> 3;            // 0..63
  const int bh = xcd * 4 + (idx >> 4); // 0..31
  const int pidx = idx & 15;           // pair index 0..15
  const int b = bh >> 4, h = bh & 15;

  const u16* Qg = qkv + (size_t)(b * 2048) * 3072 + h * 64;
  const u16* Kg = Qg + 1024;
  const u16* Vg = Qg + 2048;

  const int slotA = tid, slotB = 256 + tid;
  const int srA = slotA >> 3, srB = slotB >> 3;
  const int scA = (((slotA & 7) * 16) ^ sw(srA)) >> 1;
  const int scB = (((slotB & 7) * 16) ^ sw(srB)) >> 1;
  const int t2 = tid >> 3;
  const int d8 = (tid & 7) * 8;

  bf16x8 vone;
#pragma unroll
  for (int j = 0; j < 8; ++j) vone[j] = (short)0x3F80;

  const int trow = tsub * 32 + l31;
  int koff[4];
#pragma unroll
  for (int ks = 0; ks < 4; ++ks)
    koff[ks] = trow * 128 + (((ks * 16 + hi * 8) * 2) ^ sw(trow));
  int voff[2][2];
#pragma unroll
  for (int db = 0; db < 2; ++db) {
    const int dl = db * 32 + l31;
#pragma unroll
    for (int ks = 0; ks < 2; ++ks)
      voff[db][ks] = dl * 128 + (((tsub * 32 + ks * 16 + hi * 8) * 2) ^ sw(dl));
  }

  for (int pass = 0; pass < 2; ++pass) {
    const int qi = pass ? (31 - pidx) : pidx;   // q-tile (64 rows), 0..31
    const int nt = qi + 1;                      // # of 64-row KV tiles
    const int qb = qi * 64;
    const int qrow = qb + qsub * 32 + l31;

    bf16x8 aq[4];
#pragma unroll
    for (int ks = 0; ks < 4; ++ks) {
      bf16x8 v = *(const bf16x8*)&Qg[(size_t)qrow * 3072 + ks * 16 + hi * 8];
#pragma unroll
      for (int j = 0; j < 8; ++j)
        v[j] = (short)f2b(b2f((u16)v[j]) * 0.18033688011112042f);
      aq[ks] = v;
    }

    f32x16 acc0 = {}, acc1 = {}, accl = {};

    // --- prologue: V0,V1 reg loads; K0,K1 gll (K newest in queue) ---
    bf16x8 va0, va1;
    {
      const int t1c = (1 < qi ? 1 : qi) * 64;
      bf16x8 v00 = *(const bf16x8*)&Vg[(size_t)(2 * t2) * 3072 + d8];
      bf16x8 v01 = *(const bf16x8*)&Vg[(size_t)(2 * t2 + 1) * 3072 + d8];
      va0 = *(const bf16x8*)&Vg[(size_t)(t1c + 2 * t2) * 3072 + d8];
      va1 = *(const bf16x8*)&Vg[(size_t)(t1c + 2 * t2 + 1) * 3072 + d8];
      gll16(Kg + (size_t)srA * 3072 + scA, (u16*)KlB + slotA * 8);
      gll16(Kg + (size_t)srB * 3072 + scB, (u16*)KlB + slotB * 8);
      gll16(Kg + (size_t)(t1c + srA) * 3072 + scA, (u16*)(KlB + 8192) + slotA * 8);
      gll16(Kg + (size_t)(t1c + srB) * 3072 + scB, (u16*)(KlB + 8192) + slotB * 8);
#pragma unroll
      for (int j = 0; j < 8; ++j) {
        const int d = d8 + j;
        const u32 val = (u32)(u16)v00[j] | ((u32)(u16)v01[j] << 16);
        *(u32*)(VtB + ((d * 128 + t2 * 4) ^ sw(d))) = val;
      }
    }
    asm volatile("s_waitcnt vmcnt(2) lgkmcnt(0)" ::: "memory");
    __builtin_amdgcn_s_barrier();
    __builtin_amdgcn_sched_barrier(0);

    const char* kR = KlB;
    const char* kN = KlB + 8192;
    char* kN2 = KlB + 16384;
    const char* vR = VtB;
    char* vW = VtB + 8192;

    for (int t = 0; t < nt; ++t) {
      // ---- issue V(t+2) reg loads then K(t+2) gll (clamped) ----
      const int tf = (t + 2 < 31 ? t + 2 : 31) * 64;
      const bf16x8 vf0 = *(const bf16x8*)&Vg[(size_t)(tf + 2 * t2) * 3072 + d8];
      const bf16x8 vf1 = *(const bf16x8*)&Vg[(size_t)(tf + 2 * t2 + 1) * 3072 + d8];
      gll16(Kg + (size_t)(tf + srA) * 3072 + scA, (u16*)kN2 + slotA * 8);
      gll16(Kg + (size_t)(tf + srB) * 3072 + scB, (u16*)kN2 + slotB * 8);

      // ---- S^T = K Q^T (32x32): lane col q, rows t_local ----
      f32x16 s = {};
      __builtin_amdgcn_s_setprio(1);
#pragma unroll
      for (int ks = 0; ks < 4; ++ks) {
        const bf16x8 kf = *(const bf16x8*)(kR + koff[ks]);
        s = MFMA32(kf, aq[ks], s);
      }
      __builtin_amdgcn_s_setprio(0);

      // ---- max-free softmax numerator (diagonal tile = last only) ----
      float p[16];
      if (t == nt - 1) {
#pragma unroll
        for (int r = 0; r < 16; ++r) {
          const int kkg = t * 64 + tsub * 32 + (r & 3) + 8 * (r >> 2) + 4 * hi;
          p[r] = exp2f(kkg > qrow ? -1e30f : s[r]);
        }
      } else {
#pragma unroll
        for (int r = 0; r < 16; ++r) p[r] = exp2f(s[r]);
      }

      // ---- in-register P -> PV B-frags (cvtpk + shfl_xor(32)) ----
      const u32 X0 = cvtpk(p[0], p[1]),   X1 = cvtpk(p[2], p[3]);
      const u32 X2 = cvtpk(p[4], p[5]),   X3 = cvtpk(p[6], p[7]);
      const u32 X4 = cvtpk(p[8], p[9]),   X5 = cvtpk(p[10], p[11]);
      const u32 X6 = cvtpk(p[12], p[13]), X7 = cvtpk(p[14], p[15]);
      const u32 sx0 = (u32)__shfl_xor((int)X0, 32);
      const u32 sx1 = (u32)__shfl_xor((int)X1, 32);
      const u32 sx2 = (u32)__shfl_xor((int)X2, 32);
      const u32 sx3 = (u32)__shfl_xor((int)X3, 32);
      const u32 sx4 = (u32)__shfl_xor((int)X4, 32);
      const u32 sx5 = (u32)__shfl_xor((int)X5, 32);
      const u32 sx6 = (u32)__shfl_xor((int)X6, 32);
      const u32 sx7 = (u32)__shfl_xor((int)X7, 32);
      union { u32x4 u; bf16x8 h; } c0, c1;
      c0.u[0] = hi ? sx2 : X0;
      c0.u[1] = hi ? sx3 : X1;
      c0.u[2] = hi ? X2 : sx0;
      c0.u[3] = hi ? X3 : sx1;
      c1.u[0] = hi ? sx6 : X4;
      c1.u[1] = hi ? sx7 : X5;
      c1.u[2] = hi ? X6 : sx4;
      c1.u[3] = hi ? X7 : sx5;
      const bf16x8 pb0 = c0.h, pb1 = c1.h;

      // ---- l += 1^T P ; O^T += V^T P ----
      const bf16x8 vb00 = *(const bf16x8*)(vR + voff[0][0]);
      const bf16x8 vb01 = *(const bf16x8*)(vR + voff[0][1]);
      const bf16x8 vb10 = *(const bf16x8*)(vR + voff[1][0]);
      const bf16x8 vb11 = *(const bf16x8*)(vR + voff[1][1]);
      __builtin_amdgcn_s_setprio(1);
      accl = MFMA32(vone, pb0, accl);
      accl = MFMA32(vone, pb1, accl);
      acc0 = MFMA32(vb00, pb0, acc0);
      acc0 = MFMA32(vb01, pb1, acc0);
      acc1 = MFMA32(vb10, pb0, acc1);
      acc1 = MFMA32(vb11, pb1, acc1);
      __builtin_amdgcn_s_setprio(0);

      // ---- publish V(t+1) regs -> LDS (write-late) ----
      if (t < nt - 1) {
#pragma unroll
        for (int j = 0; j < 8; ++j) {
          const int d = d8 + j;
          const u32 val = (u32)(u16)va0[j] | ((u32)(u16)va1[j] << 16);
          *(u32*)(vW + ((d * 128 + t2 * 4) ^ sw(d))) = val;
        }
      }
      va0 = vf0; va1 = vf1;
      const char* kt_ = kR; kR = kN; kN = kN2; kN2 = (char*)kt_;
      char* vt_ = (char*)vR; vR = vW; vW = vt_;

      // counted barrier: V(t+2)x2 + K(t+2)x2 stay in flight; K(t+1) done
      asm volatile("s_waitcnt vmcnt(4) lgkmcnt(0)" ::: "memory");
      __builtin_amdgcn_s_barrier();
      __builtin_amdgcn_sched_barrier(0);
    }

    // full drain: K/V buffers (incl. clamped junk prefetches) now dead
    asm volatile("s_waitcnt vmcnt(0) lgkmcnt(0)" ::: "memory");
    __builtin_amdgcn_s_barrier();
    __builtin_amdgcn_sched_barrier(0);

    if (tsub == 1) {
#pragma unroll
      for (int r = 0; r < 16; ++r) {
        const int d = (r & 3) + 8 * (r >> 2) + 4 * hi;
        Om[qsub][d][l31] = acc0[r];
        Om[qsub][32 + d][l31] = acc1[r];
      }
      Lm[qsub][1][l31] = accl[0];
    } else {
      Lm[qsub][0][l31] = accl[0];
    }
    __syncthreads();
    if (tsub == 0) {
      const float linv = 1.0f / (Lm[qsub][0][l31] + Lm[qsub][1][l31]);
#pragma unroll
      for (int r = 0; r < 16; ++r) {
        const int d = (r & 3) + 8 * (r >> 2) + 4 * hi;
        Om[qsub][d][l31] = (acc0[r] + Om[qsub][d][l31]) * linv;
        Om[qsub][32 + d][l31] = (acc1[r] + Om[qsub][32 + d][l31]) * linv;
      }
    }
    __syncthreads();
    {
      const int qloc = tid >> 2;           // 0..63
      const int dgr = (tid & 3) * 16;
      const size_t yo = (size_t)(b * 2048 + qb + qloc) * 1024 + h * 64 + dgr;
      u32 o[8];
#pragma unroll
      for (int jj = 0; jj < 8; ++jj)
        o[jj] = cvtpk(Om[qloc >> 5][dgr + 2 * jj][qloc & 31],
                      Om[qloc >> 5][dgr + 2 * jj + 1][qloc & 31]);
      u32x4 s0 = {o[0], o[1], o[2], o[3]};
      u32x4 s1 = {o[4], o[5], o[6], o[7]};
      *(u32x4*)&y[yo] = s0;
      *(u32x4*)&y[yo + 8] = s1;
    }
    __syncthreads();   // Om reads done before next pass overwrites K/V region
  }
}

// ---------------- host launch ----------------
extern "C" void kernel_launch(void* const* d_in, const int* in_sizes, int n_in,
                              void* d_out, int out_size, void* d_ws, size_t ws_size,
                              hipStream_t stream) {
  const float* x  = (const float*)d_in[0];   // [2,2048,1024]
  const float* wa = (const float*)d_in[1];   // [1024,3072]
  const float* wp = (const float*)d_in[2];   // [1024,1024]
  float* out = (float*)d_out;                // [2,2048,1024] fp32

  u16* xb  = (u16*)d_ws;                 // [4096][1024] bf16
  u16* wat = xb + (size_t)4096 * 1024;   // [3072][1024] bf16 (w_attn^T)
  u16* wpt = wat + (size_t)3072 * 1024;  // [1024][1024] bf16 (w_proj^T)
  u16* qkv = wpt + (size_t)1024 * 1024;  // [4096][3072] bf16
  u16* yb  = qkv + (size_t)4096 * 3072;  // [4096][1024] bf16

  // fused prep: cvt(x) + transpose-cvt(wa) + transpose-cvt(wp)
  k_prep<<<5120, 256, 0, stream>>>(x, xb, wa, wat, wp, wpt);

  // qkv = x @ w_attn   (bf16 out) -- 256x192 tile, phase-interleaved
  k_gemm1<<<256, 512, 0, stream>>>(xb, wat, qkv);

  // fused causal attention -> y [4096][1024] bf16 (v13)
  k_attn<<<512, 256, 0, stream>>>(qkv, yb);

  // out = y @ w_proj   (fp32 out) -- 128x128 tile, phase-interleaved
  k_gemm2<<<256, 256, 0, stream>>>(yb, wpt, out);
}

// Round 19
// 101.523 us; speedup vs baseline: 1.0366x; 1.0366x over previous
//
#include <hip/hip_runtime.h>
#include <hip/hip_bf16.h>
#include <stdint.h>

typedef unsigned short u16;
typedef unsigned int u32;
typedef unsigned long long u64;
typedef float f32x4 __attribute__((ext_vector_type(4)));
typedef float f32x16 __attribute__((ext_vector_type(16)));
typedef short bf16x8 __attribute__((ext_vector_type(8)));
typedef u32 u32x4 __attribute__((ext_vector_type(4)));

#define MFMA(a, b, c) __builtin_amdgcn_mfma_f32_16x16x32_bf16((a), (b), (c), 0, 0, 0)
#define MFMA32(a, b, c) __builtin_amdgcn_mfma_f32_32x32x16_bf16((a), (b), (c), 0, 0, 0)

__device__ __forceinline__ void gll16(const void* g, void* lds) {
  __builtin_amdgcn_global_load_lds(
      (const __attribute__((address_space(1))) u32*)(uintptr_t)g,
      (__attribute__((address_space(3))) u32*)(uintptr_t)lds, 16, 0, 0);
}

__device__ __forceinline__ u16 f2b(float f) {
  union { __hip_bfloat16 h; u16 u; } cv;
  cv.h = __float2bfloat16(f);
  return cv.u;
}
__device__ __forceinline__ float b2f(u16 b) {
  union { u32 u; float f; } cv;
  cv.u = (u32)b << 16;
  return cv.f;
}
__device__ __forceinline__ u32 cvtpk(float lo, float hi) {
  u32 r;
  asm("v_cvt_pk_bf16_f32 %0, %1, %2" : "=v"(r) : "v"(lo), "v"(hi));
  return r;
}

// swizzle: conflict-free for both transpose-writes and column-slice reads
__device__ __forceinline__ int sw(int r) { return ((r ^ (r >> 3)) & 7) << 4; }

// ---------------- fused prep: cvt(x) + trcvt(wa) + trcvt(wp) -------------
__global__ __launch_bounds__(256) void k_prep(const float* __restrict__ x,
                                              u16* __restrict__ xb,
                                              const float* __restrict__ wa,
                                              u16* __restrict__ wat,
                                              const float* __restrict__ wp,
                                              u16* __restrict__ wpt) {
  const int bid = blockIdx.x;
  const int tid = threadIdx.x;
  if (bid < 4096) {
    const int i = bid * 256 + tid;
    const float4 v = reinterpret_cast<const float4*>(x)[i];
    u32 lo = (u32)f2b(v.x) | ((u32)f2b(v.y) << 16);
    u32 hi = (u32)f2b(v.z) | ((u32)f2b(v.w) << 16);
    reinterpret_cast<uint2*>(xb)[i] = make_uint2(lo, hi);
    return;
  }
  const float* in;
  u16* out;
  int R, C, bx, by;
  if (bid < 4864) {
    const int idx = bid - 4096;
    in = wa; out = wat; R = 1024; C = 3072;
    bx = idx % 48; by = idx / 48;
  } else {
    const int idx = bid - 4864;
    in = wp; out = wpt; R = 1024; C = 1024;
    bx = idx & 15; by = idx >> 4;
  }
  __shared__ float tile[64][65];
  const int r0 = by * 64, c0 = bx * 64;
  const int tr = tid >> 4;
  const int tc4 = (tid & 15) * 4;
#pragma unroll
  for (int i = 0; i < 4; ++i) {
    const float4 v = *reinterpret_cast<const float4*>(
        &in[(size_t)(r0 + i * 16 + tr) * C + c0 + tc4]);
    tile[i * 16 + tr][tc4 + 0] = v.x;
    tile[i * 16 + tr][tc4 + 1] = v.y;
    tile[i * 16 + tr][tc4 + 2] = v.z;
    tile[i * 16 + tr][tc4 + 3] = v.w;
  }
  __syncthreads();
#pragma unroll
  for (int i = 0; i < 4; ++i) {
    const int c = i * 16 + tr;
    const int r4 = tc4;
    u32 lo = (u32)f2b(tile[r4 + 0][c]) | ((u32)f2b(tile[r4 + 1][c]) << 16);
    u32 hi = (u32)f2b(tile[r4 + 2][c]) | ((u32)f2b(tile[r4 + 3][c]) << 16);
    *reinterpret_cast<uint2*>(&out[(size_t)(c0 + c) * R + r0 + r4]) =
        make_uint2(lo, hi);
  }
}

// ---------------- GEMM1: qkv = x @ w_attn, 4096x3072x1024 ----------------
// 256x192 tile, 512 thr / 8 waves, BK=64, dbuf LDS, 4-phase interleave.
__global__ __launch_bounds__(512, 1) void k_gemm1(const u16* __restrict__ A,
                                                  const u16* __restrict__ Bt,
                                                  u16* __restrict__ C) {
  __shared__ u16 As[2][256 * 64];  // 32KB each, rows 128B, sw-swizzled
  __shared__ u16 Bs[2][192 * 64];  // 24KB each
  const int tid = threadIdx.x;
  const int lane = tid & 63;
  const int w = tid >> 6;
  const int wm = w >> 2, wn = w & 3;
  const int l15 = lane & 15, lg = lane >> 4;

  const int bid = blockIdx.x;                 // 0..255
  const int lin = (bid & 7) * 32 + (bid >> 3);  // XCD-chunked
  const int bm = lin >> 4, bn = lin & 15;
  const size_t brow = (size_t)bm * 256, bcol = (size_t)bn * 192;

  const int sr = tid >> 3;                  // 0..63
  const int scb = (tid & 7) * 16;           // bytes
  const int gcol = (scb ^ sw(sr)) >> 1;     // u16 units
  const u16* Ag[4];
#pragma unroll
  for (int i = 0; i < 4; ++i) Ag[i] = A + (brow + i * 64 + sr) * 1024 + gcol;
  const u16* Bg[3];
#pragma unroll
  for (int i = 0; i < 3; ++i) Bg[i] = Bt + (bcol + i * 64 + sr) * 1024 + gcol;

  f32x4 acc[8][3] = {};

#pragma unroll
  for (int i = 0; i < 4; ++i) gll16(Ag[i], (char*)As[0] + i * 8192 + tid * 16);
#pragma unroll
  for (int i = 0; i < 3; ++i) gll16(Bg[i], (char*)Bs[0] + i * 8192 + tid * 16);
  asm volatile("s_waitcnt vmcnt(0) lgkmcnt(0)" ::: "memory");
  __builtin_amdgcn_s_barrier();
  __builtin_amdgcn_sched_barrier(0);

  for (int kt = 0; kt < 16; ++kt) {
    const int cur = kt & 1;
    const char* as = (const char*)As[cur];
    const char* bs = (const char*)Bs[cur];
    char* asn = (char*)As[cur ^ 1];
    char* bsn = (char*)Bs[cur ^ 1];
    const bool more = (kt + 1 < 16);
    const int ko = (kt + 1) * 64;

    bf16x8 bfr[3][2];
#pragma unroll
    for (int n = 0; n < 3; ++n) {
      const int row = wn * 48 + n * 16 + l15;
#pragma unroll
      for (int kh = 0; kh < 2; ++kh)
        bfr[n][kh] = *(const bf16x8*)(bs + row * 128 +
                                      ((kh * 64 + lg * 16) ^ sw(row)));
    }
#define GPHASE(MB, STAGE_A, STAGE_B, LAST)                                    \
    {                                                                         \
      bf16x8 af[2][2];                                                        \
      _Pragma("unroll")                                                       \
      for (int mm = 0; mm < 2; ++mm) {                                        \
        const int row = wm * 128 + (MB + mm) * 16 + l15;                      \
        _Pragma("unroll")                                                     \
        for (int kh = 0; kh < 2; ++kh)                                        \
          af[mm][kh] = *(const bf16x8*)(as + row * 128 +                      \
                                        ((kh * 64 + lg * 16) ^ sw(row)));     \
      }                                                                       \
      if (STAGE_A && more) {                                                  \
        _Pragma("unroll")                                                     \
        for (int i = 0; i < 4; ++i)                                           \
          gll16(Ag[i] + ko, asn + i * 8192 + tid * 16);                       \
      }                                                                       \
      if (STAGE_B && more) {                                                  \
        _Pragma("unroll")                                                     \
        for (int i = 0; i < 3; ++i)                                           \
          gll16(Bg[i] + ko, bsn + i * 8192 + tid * 16);                       \
      }                                                                       \
      __builtin_amdgcn_s_setprio(1);                                          \
      _Pragma("unroll")                                                       \
      for (int mm = 0; mm < 2; ++mm)                                          \
        _Pragma("unroll")                                                     \
        for (int n = 0; n < 3; ++n) {                                         \
          acc[MB + mm][n] = MFMA(af[mm][0], bfr[n][0], acc[MB + mm][n]);      \
          acc[MB + mm][n] = MFMA(af[mm][1], bfr[n][1], acc[MB + mm][n]);      \
        }                                                                     \
      __builtin_amdgcn_s_setprio(0);                                          \
      if (LAST) {                                                             \
        asm volatile("s_waitcnt vmcnt(0) lgkmcnt(0)" ::: "memory");           \
      }                                                                       \
      __builtin_amdgcn_s_barrier();                                           \
    }
    GPHASE(0, 1, 0, 0)
    GPHASE(2, 0, 1, 0)
    GPHASE(4, 0, 0, 0)
    GPHASE(6, 0, 0, 1)
#undef GPHASE
    __builtin_amdgcn_sched_barrier(0);
  }

#pragma unroll
  for (int m = 0; m < 8; ++m) {
    const size_t row = brow + wm * 128 + m * 16 + lg * 4;
#pragma unroll
    for (int n = 0; n < 3; ++n) {
      const size_t col = bcol + wn * 48 + n * 16 + l15;
#pragma unroll
      for (int r = 0; r < 4; ++r)
        C[(row + r) * 3072 + col] = f2b(acc[m][n][r]);
    }
  }
}

// ---------------- GEMM2: out = y @ w_proj, 4096x1024x1024, fp32 out ------
__global__ __launch_bounds__(256) void k_gemm2(const u16* __restrict__ A,
                                               const u16* __restrict__ Bt,
                                               float* __restrict__ C) {
  __shared__ u16 As[2][128 * 64];
  __shared__ u16 Bs[2][128 * 64];
  const int tid = threadIdx.x;
  const int lane = tid & 63;
  const int w = tid >> 6;
  const int wm = w >> 1, wn = w & 1;
  const int l15 = lane & 15, lg = lane >> 4;

  const int bid = blockIdx.x;
  const int lin = (bid & 7) * 32 + (bid >> 3);
  const int bm = lin >> 3, bn = lin & 7;
  const size_t brow = (size_t)bm * 128, bcol = (size_t)bn * 128;

  const int sr = tid >> 3;
  const int scb = (tid & 7) * 16;
  const u16* Ag[4];
  const u16* Bg[4];
#pragma unroll
  for (int i = 0; i < 4; ++i) {
    const int row = i * 32 + sr;
    const int gcol = (scb ^ sw(row)) >> 1;
    Ag[i] = A + (brow + row) * 1024 + gcol;
    Bg[i] = Bt + (bcol + row) * 1024 + gcol;
  }

  f32x4 acc[4][4] = {};

#pragma unroll
  for (int i = 0; i < 4; ++i) gll16(Ag[i], (char*)As[0] + i * 4096 + tid * 16);
#pragma unroll
  for (int i = 0; i < 4; ++i) gll16(Bg[i], (char*)Bs[0] + i * 4096 + tid * 16);
  asm volatile("s_waitcnt vmcnt(0) lgkmcnt(0)" ::: "memory");
  __builtin_amdgcn_s_barrier();
  __builtin_amdgcn_sched_barrier(0);

  for (int kt = 0; kt < 16; ++kt) {
    const int cur = kt & 1;
    const char* as = (const char*)As[cur];
    const char* bs = (const char*)Bs[cur];
    char* asn = (char*)As[cur ^ 1];
    char* bsn = (char*)Bs[cur ^ 1];
    const bool more = (kt + 1 < 16);
    const int ko = (kt + 1) * 64;

    bf16x8 bfr[4][2];
#pragma unroll
    for (int n = 0; n < 4; ++n) {
      const int row = wn * 64 + n * 16 + l15;
#pragma unroll
      for (int kh = 0; kh < 2; ++kh)
        bfr[n][kh] = *(const bf16x8*)(bs + row * 128 +
                                      ((kh * 64 + lg * 16) ^ sw(row)));
    }
#define G2PHASE(MB, STAGE_A, STAGE_B, LAST)                                   \
    {                                                                         \
      bf16x8 af[2];                                                           \
      {                                                                       \
        const int row = wm * 64 + (MB) * 16 + l15;                            \
        _Pragma("unroll")                                                     \
        for (int kh = 0; kh < 2; ++kh)                                        \
          af[kh] = *(const bf16x8*)(as + row * 128 +                          \
                                    ((kh * 64 + lg * 16) ^ sw(row)));         \
      }                                                                       \
      if (STAGE_A && more) {                                                  \
        _Pragma("unroll")                                                     \
        for (int i = 0; i < 4; ++i)                                           \
          gll16(Ag[i] + ko, asn + i * 4096 + tid * 16);                       \
      }                                                                       \
      if (STAGE_B && more) {                                                  \
        _Pragma("unroll")                                                     \
        for (int i = 0; i < 4; ++i)                                           \
          gll16(Bg[i] + ko, bsn + i * 4096 + tid * 16);                       \
      }                                                                       \
      __builtin_amdgcn_s_setprio(1);                                          \
      _Pragma("unroll")                                                       \
      for (int n = 0; n < 4; ++n) {                                           \
        acc[MB][n] = MFMA(af[0], bfr[n][0], acc[MB][n]);                      \
        acc[MB][n] = MFMA(af[1], bfr[n][1], acc[MB][n]);                      \
      }                                                                       \
      __builtin_amdgcn_s_setprio(0);                                          \
      if (LAST) {                                                             \
        asm volatile("s_waitcnt vmcnt(0) lgkmcnt(0)" ::: "memory");           \
      }                                                                       \
      __builtin_amdgcn_s_barrier();                                           \
    }
    G2PHASE(0, 1, 0, 0)
    G2PHASE(1, 0, 1, 0)
    G2PHASE(2, 0, 0, 0)
    G2PHASE(3, 0, 0, 1)
#undef G2PHASE
    __builtin_amdgcn_sched_barrier(0);
  }

#pragma unroll
  for (int m = 0; m < 4; ++m) {
    const size_t row = brow + wm * 64 + m * 16 + lg * 4;
#pragma unroll
    for (int n = 0; n < 4; ++n) {
      const size_t col = bcol + wn * 64 + n * 16 + l15;
#pragma unroll
      for (int r = 0; r < 4; ++r)
        C[(row + r) * 1024 + col] = acc[m][n][r];
    }
  }
}

// ---------------- fused causal flash attention (v12 — best, no setprio) --
// 512 blocks x 256 thr (4 waves), 64-row q-tiles paired (k,31-k) -> 33
// uniform steps, 2 desynced blocks/CU (40KB LDS, O-merge aliased).
__global__ __launch_bounds__(256, 2) void k_attn(const u16* __restrict__ qkv,
                                                 u16* __restrict__ y) {
  __shared__ char smem[40960];
  char* KlB = smem;                 // 3 x 8192  [t][d] sw(t)
  char* VtB = smem + 24576;         // 2 x 8192  [d][t] sw(d)
  float (*Om)[64][33] = (float (*)[64][33])smem;         // epilogue alias
  float (*Lm)[2][32] = (float (*)[2][32])(smem + 16896); // 512B

  const int tid = threadIdx.x;
  const int lane = tid & 63;
  const int w = tid >> 6;            // 0..3
  const int qsub = w & 1, tsub = w >> 1;
  const int l31 = lane & 31, hi = lane >> 5;

  const int bid = blockIdx.x;          // 0..511
  const int xcd = bid & 7;
  const int idx = bid >> 3;            // 0..63
  const int bh = xcd * 4 + (idx >> 4); // 0..31
  const int pidx = idx & 15;           // pair index 0..15
  const int b = bh >> 4, h = bh & 15;

  const u16* Qg = qkv + (size_t)(b * 2048) * 3072 + h * 64;
  const u16* Kg = Qg + 1024;
  const u16* Vg = Qg + 2048;

  const int slotA = tid, slotB = 256 + tid;
  const int srA = slotA >> 3, srB = slotB >> 3;
  const int scA = (((slotA & 7) * 16) ^ sw(srA)) >> 1;
  const int scB = (((slotB & 7) * 16) ^ sw(srB)) >> 1;
  const int t2 = tid >> 3;
  const int d8 = (tid & 7) * 8;

  bf16x8 vone;
#pragma unroll
  for (int j = 0; j < 8; ++j) vone[j] = (short)0x3F80;

  const int trow = tsub * 32 + l31;
  int koff[4];
#pragma unroll
  for (int ks = 0; ks < 4; ++ks)
    koff[ks] = trow * 128 + (((ks * 16 + hi * 8) * 2) ^ sw(trow));
  int voff[2][2];
#pragma unroll
  for (int db = 0; db < 2; ++db) {
    const int dl = db * 32 + l31;
#pragma unroll
    for (int ks = 0; ks < 2; ++ks)
      voff[db][ks] = dl * 128 + (((tsub * 32 + ks * 16 + hi * 8) * 2) ^ sw(dl));
  }

  for (int pass = 0; pass < 2; ++pass) {
    const int qi = pass ? (31 - pidx) : pidx;   // q-tile (64 rows), 0..31
    const int nt = qi + 1;                      // # of 64-row KV tiles
    const int qb = qi * 64;
    const int qrow = qb + qsub * 32 + l31;

    bf16x8 aq[4];
#pragma unroll
    for (int ks = 0; ks < 4; ++ks) {
      bf16x8 v = *(const bf16x8*)&Qg[(size_t)qrow * 3072 + ks * 16 + hi * 8];
#pragma unroll
      for (int j = 0; j < 8; ++j)
        v[j] = (short)f2b(b2f((u16)v[j]) * 0.18033688011112042f);
      aq[ks] = v;
    }

    f32x16 acc0 = {}, acc1 = {}, accl = {};

    // --- prologue: V0,V1 reg loads; K0,K1 gll (K newest in queue) ---
    bf16x8 va0, va1;
    {
      const int t1c = (1 < qi ? 1 : qi) * 64;  // valid tile even when nt==1
      bf16x8 v00 = *(const bf16x8*)&Vg[(size_t)(2 * t2) * 3072 + d8];
      bf16x8 v01 = *(const bf16x8*)&Vg[(size_t)(2 * t2 + 1) * 3072 + d8];
      va0 = *(const bf16x8*)&Vg[(size_t)(t1c + 2 * t2) * 3072 + d8];
      va1 = *(const bf16x8*)&Vg[(size_t)(t1c + 2 * t2 + 1) * 3072 + d8];
      gll16(Kg + (size_t)srA * 3072 + scA, (u16*)KlB + slotA * 8);
      gll16(Kg + (size_t)srB * 3072 + scB, (u16*)KlB + slotB * 8);
      gll16(Kg + (size_t)(t1c + srA) * 3072 + scA, (u16*)(KlB + 8192) + slotA * 8);
      gll16(Kg + (size_t)(t1c + srB) * 3072 + scB, (u16*)(KlB + 8192) + slotB * 8);
#pragma unroll
      for (int j = 0; j < 8; ++j) {
        const int d = d8 + j;
        const u32 val = (u32)(u16)v00[j] | ((u32)(u16)v01[j] << 16);
        *(u32*)(VtB + ((d * 128 + t2 * 4) ^ sw(d))) = val;
      }
    }
    // K0 done (only K1's 2 gll may remain in flight)
    asm volatile("s_waitcnt vmcnt(2) lgkmcnt(0)" ::: "memory");
    __builtin_amdgcn_s_barrier();
    __builtin_amdgcn_sched_barrier(0);

    const char* kR = KlB;
    const char* kN = KlB + 8192;
    char* kN2 = KlB + 16384;
    const char* vR = VtB;
    char* vW = VtB + 8192;

    for (int t = 0; t < nt; ++t) {
      // ---- issue V(t+2) reg loads then K(t+2) gll (clamped) ----
      const int tf = (t + 2 < 31 ? t + 2 : 31) * 64;
      const bf16x8 vf0 = *(const bf16x8*)&Vg[(size_t)(tf + 2 * t2) * 3072 + d8];
      const bf16x8 vf1 = *(const bf16x8*)&Vg[(size_t)(tf + 2 * t2 + 1) * 3072 + d8];
      gll16(Kg + (size_t)(tf + srA) * 3072 + scA, (u16*)kN2 + slotA * 8);
      gll16(Kg + (size_t)(tf + srB) * 3072 + scB, (u16*)kN2 + slotB * 8);

      // ---- S^T = K Q^T (32x32): lane col q, rows t_local ----
      f32x16 s = {};
#pragma unroll
      for (int ks = 0; ks < 4; ++ks) {
        const bf16x8 kf = *(const bf16x8*)(kR + koff[ks]);
        s = MFMA32(kf, aq[ks], s);
      }

      // ---- max-free softmax numerator (diagonal tile = last only) ----
      float p[16];
      if (t == nt - 1) {
#pragma unroll
        for (int r = 0; r < 16; ++r) {
          const int kkg = t * 64 + tsub * 32 + (r & 3) + 8 * (r >> 2) + 4 * hi;
          p[r] = exp2f(kkg > qrow ? -1e30f : s[r]);
        }
      } else {
#pragma unroll
        for (int r = 0; r < 16; ++r) p[r] = exp2f(s[r]);
      }

      // ---- in-register P -> PV B-frags (cvtpk + shfl_xor(32)) ----
      const u32 X0 = cvtpk(p[0], p[1]),   X1 = cvtpk(p[2], p[3]);
      const u32 X2 = cvtpk(p[4], p[5]),   X3 = cvtpk(p[6], p[7]);
      const u32 X4 = cvtpk(p[8], p[9]),   X5 = cvtpk(p[10], p[11]);
      const u32 X6 = cvtpk(p[12], p[13]), X7 = cvtpk(p[14], p[15]);
      const u32 sx0 = (u32)__shfl_xor((int)X0, 32);
      const u32 sx1 = (u32)__shfl_xor((int)X1, 32);
      const u32 sx2 = (u32)__shfl_xor((int)X2, 32);
      const u32 sx3 = (u32)__shfl_xor((int)X3, 32);
      const u32 sx4 = (u32)__shfl_xor((int)X4, 32);
      const u32 sx5 = (u32)__shfl_xor((int)X5, 32);
      const u32 sx6 = (u32)__shfl_xor((int)X6, 32);
      const u32 sx7 = (u32)__shfl_xor((int)X7, 32);
      union { u32x4 u; bf16x8 h; } c0, c1;
      c0.u[0] = hi ? sx2 : X0;
      c0.u[1] = hi ? sx3 : X1;
      c0.u[2] = hi ? X2 : sx0;
      c0.u[3] = hi ? X3 : sx1;
      c1.u[0] = hi ? sx6 : X4;
      c1.u[1] = hi ? sx7 : X5;
      c1.u[2] = hi ? X6 : sx4;
      c1.u[3] = hi ? X7 : sx5;
      const bf16x8 pb0 = c0.h, pb1 = c1.h;

      // ---- l += 1^T P ; O^T += V^T P ----
      accl = MFMA32(vone, pb0, accl);
      accl = MFMA32(vone, pb1, accl);
      const bf16x8 vb00 = *(const bf16x8*)(vR + voff[0][0]);
      const bf16x8 vb01 = *(const bf16x8*)(vR + voff[0][1]);
      const bf16x8 vb10 = *(const bf16x8*)(vR + voff[1][0]);
      const bf16x8 vb11 = *(const bf16x8*)(vR + voff[1][1]);
      acc0 = MFMA32(vb00, pb0, acc0);
      acc0 = MFMA32(vb01, pb1, acc0);
      acc1 = MFMA32(vb10, pb0, acc1);
      acc1 = MFMA32(vb11, pb1, acc1);

      // ---- publish V(t+1) regs -> LDS (write-late) ----
      if (t < nt - 1) {
#pragma unroll
        for (int j = 0; j < 8; ++j) {
          const int d = d8 + j;
          const u32 val = (u32)(u16)va0[j] | ((u32)(u16)va1[j] << 16);
          *(u32*)(vW + ((d * 128 + t2 * 4) ^ sw(d))) = val;
        }
      }
      va0 = vf0; va1 = vf1;
      const char* kt_ = kR; kR = kN; kN = kN2; kN2 = (char*)kt_;
      char* vt_ = (char*)vR; vR = vW; vW = vt_;

      // counted barrier: V(t+2)x2 + K(t+2)x2 stay in flight; K(t+1) done
      asm volatile("s_waitcnt vmcnt(4) lgkmcnt(0)" ::: "memory");
      __builtin_amdgcn_s_barrier();
      __builtin_amdgcn_sched_barrier(0);
    }

    // full drain: K/V buffers (incl. clamped junk prefetches) now dead;
    // Om/Lm may alias them.
    asm volatile("s_waitcnt vmcnt(0) lgkmcnt(0)" ::: "memory");
    __builtin_amdgcn_s_barrier();
    __builtin_amdgcn_sched_barrier(0);

    if (tsub == 1) {
#pragma unroll
      for (int r = 0; r < 16; ++r) {
        const int d = (r & 3) + 8 * (r >> 2) + 4 * hi;
        Om[qsub][d][l31] = acc0[r];
        Om[qsub][32 + d][l31] = acc1[r];
      }
      Lm[qsub][1][l31] = accl[0];
    } else {
      Lm[qsub][0][l31] = accl[0];
    }
    __syncthreads();
    if (tsub == 0) {
      const float linv = 1.0f / (Lm[qsub][0][l31] + Lm[qsub][1][l31]);
#pragma unroll
      for (int r = 0; r < 16; ++r) {
        const int d = (r & 3) + 8 * (r >> 2) + 4 * hi;
        Om[qsub][d][l31] = (acc0[r] + Om[qsub][d][l31]) * linv;
        Om[qsub][32 + d][l31] = (acc1[r] + Om[qsub][32 + d][l31]) * linv;
      }
    }
    __syncthreads();
    {
      // coalesced y store: 256 thr cover 64 q-rows x 4 d-groups
      const int qloc = tid >> 2;           // 0..63
      const int dgr = (tid & 3) * 16;
      const size_t yo = (size_t)(b * 2048 + qb + qloc) * 1024 + h * 64 + dgr;
      u32 o[8];
#pragma unroll
      for (int jj = 0; jj < 8; ++jj)
        o[jj] = cvtpk(Om[qloc >> 5][dgr + 2 * jj][qloc & 31],
                      Om[qloc >> 5][dgr + 2 * jj + 1][qloc & 31]);
      u32x4 s0 = {o[0], o[1], o[2], o[3]};
      u32x4 s1 = {o[4], o[5], o[6], o[7]};
      *(u32x4*)&y[yo] = s0;
      *(u32x4*)&y[yo + 8] = s1;
    }
    __syncthreads();   // Om reads done before next pass overwrites K/V region
  }
}

// ---------------- host launch ----------------
extern "C" void kernel_launch(void* const* d_in, const int* in_sizes, int n_in,
                              void* d_out, int out_size, void* d_ws, size_t ws_size,
                              hipStream_t stream) {
  const float* x  = (const float*)d_in[0];   // [2,2048,1024]
  const float* wa = (const float*)d_in[1];   // [1024,3072]
  const float* wp = (const float*)d_in[2];   // [1024,1024]
  float* out = (float*)d_out;                // [2,2048,1024] fp32

  u16* xb  = (u16*)d_ws;                 // [4096][1024] bf16
  u16* wat = xb + (size_t)4096 * 1024;   // [3072][1024] bf16 (w_attn^T)
  u16* wpt = wat + (size_t)3072 * 1024;  // [1024][1024] bf16 (w_proj^T)
  u16* qkv = wpt + (size_t)1024 * 1024;  // [4096][3072] bf16
  u16* yb  = qkv + (size_t)4096 * 3072;  // [4096][1024] bf16

  // fused prep: cvt(x) + transpose-cvt(wa) + transpose-cvt(wp)
  k_prep<<<5120, 256, 0, stream>>>(x, xb, wa, wat, wp, wpt);

  // qkv = x @ w_attn   (bf16 out) -- 256x192 tile, phase-interleaved
  k_gemm1<<<256, 512, 0, stream>>>(xb, wat, qkv);

  // fused causal attention -> y [4096][1024] bf16 (v12, no setprio)
  k_attn<<<512, 256, 0, stream>>>(qkv, yb);

  // out = y @ w_proj   (fp32 out) -- 128x128 tile, phase-interleaved
  k_gemm2<<<256, 256, 0, stream>>>(yb, wpt, out);
}